// Round 3
// baseline (21694.200 us; speedup 1.0000x reference)
//
#include <hip/hip_runtime.h>
#include <hip/hip_cooperative_groups.h>

namespace cg = cooperative_groups;

#define BB 16
#define TT 2048
#define HIDN 896
#define HALFN 448
#define NBINS 256
#define NWG 112
#define NTHR 256
#define CPW 8               /* h-cols per WG */
#define LSTR 904            /* padded ushort stride */

typedef __attribute__((ext_vector_type(8))) short short8;
typedef __attribute__((ext_vector_type(4))) float f32x4;

__device__ __forceinline__ unsigned short f2bf(float x) {
    unsigned int u = __float_as_uint(x);
    unsigned int r = u + 0x7FFFu + ((u >> 16) & 1u);
    return (unsigned short)(r >> 16);
}

// ---------------------------------------------------------------------------
// Persistent GRU scan, tag-in-value h exchange.
// 112 WGs x 256 thr. WG g owns h-cols [8g,8g+8): 24 outputs x 16 batches.
// Wave0: MFMA tile jj=0..15 (gates r,z). Wave1: tile jj=16..31 (gate n, 8 real).
// h element = u32: (bf16(h) << 16) | (step & 0xffff). Double-buffered by
// step parity. Consumers poll tags directly -- barrier IS the data arrival.
// No fences: tag+data are atomic per u32.
// ---------------------------------------------------------------------------
__global__ __launch_bounds__(NTHR, 1)
void scan_kernel(const float* __restrict__ cond,
                 const int*   __restrict__ sig,
                 const int*   __restrict__ tcrs,
                 const float* __restrict__ Wc,
                 const float* __restrict__ Wf,
                 const float* __restrict__ Whh,
                 const float* __restrict__ b_ih,
                 const float* __restrict__ b_hh,
                 unsigned* __restrict__ htag,     // [2][16][896] u32
                 unsigned short* __restrict__ hc_out,
                 float* __restrict__ lasth)
{
    __shared__ unsigned short sW[32 * LSTR];   // B tiles: [jj][k] bf16 (24 real)
    __shared__ unsigned short sH[16 * LSTR];   // A tile:  [b][k]  bf16
    __shared__ float rz[2][BB][CPW];

    const int tid  = threadIdx.x;
    const int wg   = blockIdx.x;
    const int col0 = wg * CPW;

    // ---- one-time: W slice -> LDS bf16 ----
    for (int idx = tid; idx < 32 * HIDN; idx += NTHR) {
        int jj = idx & 31, k = idx >> 5;
        unsigned short wv = 0;
        if (jj < 24)
            wv = f2bf(Whh[(size_t)k * 2688 + (jj >> 3) * HIDN + col0 + (jj & 7)]);
        sW[jj * LSTR + k] = wv;
    }
    // ---- zero sH (h0 = 0) ----
    for (int idx = tid; idx < (16 * LSTR) / 2; idx += NTHR)
        ((unsigned*)sH)[idx] = 0;
    // ---- clear own tag slice, both parities (replay safety) ----
    {
        int p = tid >> 7, r = tid & 127;
        int b = r >> 3, c = r & 7;
        htag[p * (BB * HIDN) + b * HIDN + col0 + c] = 0x0000FFFFu;
    }

    // ---- per-lane roles ----
    const int w  = tid >> 6;      // wave 0..3
    const int l  = tid & 63;
    const int hi = l >> 4;        // batch group
    int gate = 0, c = 0;
    if (w == 0) { gate = (l & 15) >> 3; c = l & 7; }
    else if (w == 1) { gate = 2; c = l & 15; }
    const bool xrole = (w == 0) || (w == 1 && c < 8);
    const int col  = col0 + (c & 7);
    const int gcol = gate * HIDN + col;

    float wp0 = 0.f, wp1 = 0.f, wp2 = 0.f, bi = 0.f, bh = 0.f;
    if (xrole) {
        if (col < HALFN) {
            wp0 = Wc[gate * HALFN + col];
            wp1 = Wc[1344 + gate * HALFN + col];
        } else {
            int ck = col - HALFN;
            wp0 = Wf[gate * HALFN + ck];
            wp1 = Wf[1344 + gate * HALFN + ck];
            wp2 = Wf[2688 + gate * HALFN + ck];
        }
        bi = b_ih[gcol];
        bh = b_hh[gcol];
    }
    float hp[4] = {0.f, 0.f, 0.f, 0.f};

    __syncthreads();
    cg::this_grid().sync();        // all clears visible before any publish

    const float inv = 1.f / 127.5f;
    const int pb = tid >> 4;       // polling: batch row 0..15
    const int pp = tid & 15;       // polling: u64 lane offset

    for (int t = 0; t < TT; ++t) {
        // ---- x_t loads (issued early, consumed after MFMA) ----
        float xc[4], s0v[4], s1v[4], s2v[4];
        if (xrole) {
            #pragma unroll
            for (int r = 0; r < 4; ++r) {
                int b = hi * 4 + r;
                size_t bt = (size_t)b * TT + t;
                xc[r]  = cond[(bt * 3 + gate) * HIDN + col];
                s0v[r] = (float)sig[bt * 2 + 0] * inv - 1.f;
                s1v[r] = (float)sig[bt * 2 + 1] * inv - 1.f;
                s2v[r] = (float)tcrs[bt] * inv - 1.f;
            }
        }

        if (t > 0) {
            // ---- poll h(t) by tag; stage into LDS as chunks arrive ----
            const unsigned tagv = (unsigned)(t & 0xffff);
            const unsigned long long* hb =
                (const unsigned long long*)(htag + (t & 1) * (BB * HIDN));
            unsigned long long v[28];
            #pragma unroll
            for (int i = 0; i < 28; ++i)
                v[i] = __hip_atomic_load(&hb[pb * 448 + pp + i * 16],
                                         __ATOMIC_RELAXED, __HIP_MEMORY_SCOPE_AGENT);
            unsigned pend = 0;
            #pragma unroll
            for (int i = 0; i < 28; ++i) {
                bool ok = (((unsigned)v[i] & 0xffffu) == tagv) &
                          (((unsigned)(v[i] >> 32) & 0xffffu) == tagv);
                int pos = pp + i * 16;
                if (ok)
                    *(unsigned*)&sH[pb * LSTR + 2 * pos] =
                        ((unsigned)(v[i] >> 16) & 0xffffu) | ((unsigned)(v[i] >> 48) << 16);
                else
                    pend |= 1u << i;
            }
            while (pend) {
                unsigned np = 0;
                #pragma unroll
                for (int i = 0; i < 28; ++i) {
                    if (pend & (1u << i)) {
                        unsigned long long vv =
                            __hip_atomic_load(&hb[pb * 448 + pp + i * 16],
                                              __ATOMIC_RELAXED, __HIP_MEMORY_SCOPE_AGENT);
                        bool ok = (((unsigned)vv & 0xffffu) == tagv) &
                                  (((unsigned)(vv >> 32) & 0xffffu) == tagv);
                        int pos = pp + i * 16;
                        if (ok)
                            *(unsigned*)&sH[pb * LSTR + 2 * pos] =
                                ((unsigned)(vv >> 16) & 0xffffu) | ((unsigned)(vv >> 48) << 16);
                        else
                            np |= 1u << i;
                    }
                }
                pend = np;
            }
        }
        __syncthreads();

        // ---- gh = h @ W : two 16x16 tiles, K=896, 28 MFMAs each ----
        f32x4 acc = {0.f, 0.f, 0.f, 0.f};
        if (w < 2) {
            const unsigned short* pa = &sH[(l & 15) * LSTR + hi * 8];
            const unsigned short* pw = &sW[((w << 4) + (l & 15)) * LSTR + hi * 8];
            #pragma unroll
            for (int ks = 0; ks < 28; ++ks) {
                short8 av = *(const short8*)(pa + ks * 32);
                short8 bv = *(const short8*)(pw + ks * 32);
                acc = __builtin_amdgcn_mfma_f32_16x16x32_bf16(av, bv, acc, 0, 0, 0);
            }
        }
        if (w == 0) {
            #pragma unroll
            for (int r = 0; r < 4; ++r) {
                float x = xc[r] + bi + s0v[r] * wp0 + s1v[r] * wp1 + s2v[r] * wp2;
                float g = x + acc[r] + bh;
                rz[gate][hi * 4 + r][c] = 1.f / (1.f + __expf(-g));
            }
        }
        __syncthreads();

        if (w == 1) {
            unsigned myu[4];
            if (c < 8) {
                const unsigned tago = (unsigned)((t + 1) & 0xffff);
                unsigned* hdst = htag + ((t + 1) & 1) * (BB * HIDN);
                #pragma unroll
                for (int r = 0; r < 4; ++r) {
                    int b = hi * 4 + r;
                    float rr = rz[0][b][c];
                    float zz = rz[1][b][c];
                    float x = xc[r] + bi + s0v[r] * wp0 + s1v[r] * wp1 + s2v[r] * wp2;
                    float a2 = x + rr * (acc[r] + bh);
                    float e = __expf(-2.f * a2);
                    float n = (1.f - e) / (1.f + e);
                    float hn = (1.f - zz) * n + zz * hp[r];
                    hp[r] = hn;
                    myu[r] = ((unsigned)f2bf(hn) << 16) | tago;
                    if (t < TT - 1)
                        __hip_atomic_store(&hdst[b * HIDN + col], myu[r],
                                           __ATOMIC_RELAXED, __HIP_MEMORY_SCOPE_AGENT);
                    else
                        lasth[(size_t)b * HIDN + col] = hn;
                }
            }
            if (wg < 56 && c < 8) {
                #pragma unroll
                for (int r = 0; r < 4; ++r) {
                    unsigned other = (unsigned)__shfl((int)myu[r], l + 1);
                    if (!(c & 1)) {
                        int b = hi * 4 + r;
                        *(unsigned*)(hc_out + ((size_t)b * TT + t) * HALFN + col) =
                            (myu[r] >> 16) | (other & 0xffff0000u);
                    }
                }
            }
        }
    }
}

// ---------------------------------------------------------------------------
// Head GEMM: C(M x N) = [relu](A_bf16(M x 448) @ Bw(448 x N) + bias)
// ---------------------------------------------------------------------------
template<int RELU_BF16>
__global__ __launch_bounds__(256)
void head_gemm(const unsigned short* __restrict__ A,
               const float* __restrict__ Bw,
               const float* __restrict__ bias,
               unsigned short* __restrict__ Cb,
               float* __restrict__ Cf,
               int N)
{
    const int K = 448;
    __shared__ float As[32][68];
    __shared__ float Bs[32][68];
    const int tid = threadIdx.x;
    const int tx = tid & 15;
    const int ty = tid >> 4;
    const int bm = blockIdx.x * 64;
    const int bn = blockIdx.y * 64;

    float acc[4][4] = {};

    for (int k0 = 0; k0 < K; k0 += 32) {
        #pragma unroll
        for (int it = 0; it < 2; ++it) {
            int idx = tid + it * 256;
            int m   = idx >> 3;
            int k4  = idx & 7;
            ushort4 av = *(const ushort4*)(A + (size_t)(bm + m) * K + k0 + k4 * 4);
            As[k4 * 4 + 0][m] = __uint_as_float((unsigned)av.x << 16);
            As[k4 * 4 + 1][m] = __uint_as_float((unsigned)av.y << 16);
            As[k4 * 4 + 2][m] = __uint_as_float((unsigned)av.z << 16);
            As[k4 * 4 + 3][m] = __uint_as_float((unsigned)av.w << 16);
        }
        #pragma unroll
        for (int it = 0; it < 2; ++it) {
            int idx = tid + it * 256;
            int k   = idx >> 4;
            int n4  = idx & 15;
            *(float4*)&Bs[k][n4 * 4] =
                *(const float4*)(Bw + (size_t)(k0 + k) * N + bn + n4 * 4);
        }
        __syncthreads();
        #pragma unroll
        for (int k = 0; k < 32; ++k) {
            float4 a4 = *(float4*)&As[k][ty * 4];
            float4 b4 = *(float4*)&Bs[k][tx * 4];
            float ar[4] = {a4.x, a4.y, a4.z, a4.w};
            float br[4] = {b4.x, b4.y, b4.z, b4.w};
            #pragma unroll
            for (int i = 0; i < 4; ++i)
                #pragma unroll
                for (int j = 0; j < 4; ++j)
                    acc[i][j] = fmaf(ar[i], br[j], acc[i][j]);
        }
        __syncthreads();
    }

    float4 bsv = *(const float4*)(bias + bn + tx * 4);
    float bb[4] = {bsv.x, bsv.y, bsv.z, bsv.w};
    #pragma unroll
    for (int i = 0; i < 4; ++i) {
        int row = bm + ty * 4 + i;
        float v[4];
        #pragma unroll
        for (int j = 0; j < 4; ++j) v[j] = acc[i][j] + bb[j];
        if (RELU_BF16) {
            ushort4 o;
            o.x = f2bf(fmaxf(v[0], 0.f));
            o.y = f2bf(fmaxf(v[1], 0.f));
            o.z = f2bf(fmaxf(v[2], 0.f));
            o.w = f2bf(fmaxf(v[3], 0.f));
            *(ushort4*)(Cb + (size_t)row * N + bn + tx * 4) = o;
        } else {
            float4 o = make_float4(v[0], v[1], v[2], v[3]);
            *(float4*)(Cf + (size_t)row * N + bn + tx * 4) = o;
        }
    }
}

// ---------------------------------------------------------------------------
extern "C" void kernel_launch(void* const* d_in, const int* in_sizes, int n_in,
                              void* d_out, int out_size, void* d_ws, size_t ws_size,
                              hipStream_t stream)
{
    const float* cond = (const float*)d_in[0];
    const int*   sig  = (const int*)d_in[1];
    const int*   tcrs = (const int*)d_in[2];
    const float* Wc   = (const float*)d_in[3];
    const float* Wf   = (const float*)d_in[4];
    const float* Whh  = (const float*)d_in[5];
    const float* bih  = (const float*)d_in[6];
    const float* bhh  = (const float*)d_in[7];
    const float* W1c  = (const float*)d_in[8];
    const float* b1c  = (const float*)d_in[9];
    const float* W2c  = (const float*)d_in[10];
    const float* b2c  = (const float*)d_in[11];
    const float* W1f  = (const float*)d_in[12];
    const float* b1f  = (const float*)d_in[13];
    const float* W2f  = (const float*)d_in[14];
    const float* b2f  = (const float*)d_in[15];

    char* ws = (char*)d_ws;
    unsigned* htag       = (unsigned*)ws;                        // 114,688 B
    unsigned short* hc   = (unsigned short*)(ws + 114688);       // 29,360,128 B
    unsigned short* hid1 = (unsigned short*)(ws + 114688 + 29360128);

    float* outc  = (float*)d_out;
    float* outf  = outc + (size_t)BB * TT * NBINS;
    float* lasth = outc + 2 * (size_t)BB * TT * NBINS;

    void* args[] = {(void*)&cond, (void*)&sig, (void*)&tcrs, (void*)&Wc, (void*)&Wf,
                    (void*)&Whh, (void*)&bih, (void*)&bhh,
                    (void*)&htag, (void*)&hc, (void*)&lasth};
    hipLaunchCooperativeKernel((void*)scan_kernel, dim3(NWG), dim3(NTHR),
                               args, 0, stream);

    dim3 blk(256);
    head_gemm<1><<<dim3(512, 7), blk, 0, stream>>>(hc,   W1c, b1c, hid1, nullptr, 448);
    head_gemm<0><<<dim3(512, 4), blk, 0, stream>>>(hid1, W2c, b2c, nullptr, outc, 256);
    head_gemm<1><<<dim3(512, 7), blk, 0, stream>>>(hc,   W1f, b1f, hid1, nullptr, 448);
    head_gemm<0><<<dim3(512, 4), blk, 0, stream>>>(hid1, W2f, b2f, nullptr, outf, 256);
}